// Round 3
// baseline (527.947 us; speedup 1.0000x reference)
//
#include <hip/hip_runtime.h>

#define TT 32

// ---------- bf16 helpers (OCP bfloat16, RNE) ----------
__device__ __forceinline__ float bf16_bits_to_f32(unsigned short u) {
    unsigned v = ((unsigned)u) << 16; float f; __builtin_memcpy(&f, &v, 4); return f;
}
__device__ __forceinline__ unsigned short f32_to_bf16_rne(float f) {
    unsigned u; __builtin_memcpy(&u, &f, 4);
    u += 0x7FFFu + ((u >> 16) & 1u);            // round-to-nearest-even
    return (unsigned short)(u >> 16);
}
__device__ __forceinline__ float round_bf16_f32(float f) {  // f32 -> bf16 -> f32 value
    return bf16_bits_to_f32(f32_to_bf16_rne(f));
}
// Correctly-rounded f64 -> bf16 (single rounding): round-to-odd to f32, then RNE.
__device__ __forceinline__ float f64_to_bf16_f32(double d) {
    float fz = __double2float_rz(d);
    if ((double)fz != d) {
        unsigned u; __builtin_memcpy(&u, &fz, 4); u |= 1u; __builtin_memcpy(&fz, &u, 4);
    }
    return round_bf16_f32(fz);
}
// Spread the 8 bits of b to positions 0,4,8,...,28 (Morton-4).
__device__ __forceinline__ unsigned spread4(unsigned b) {
    unsigned x = (b | (b << 12)) & 0x000F000Fu;
    x = (x | (x << 6)) & 0x03030303u;
    x = (x | (x << 3)) & 0x11111111u;
    return x;
}
// Register-only quad-lane exchange (DPP quad_perm), applied to f64 halves.
// 0xB1 = {1,0,3,2} (xor 1), 0x4E = {2,3,0,1} (xor 2).
template<int CTRL>
__device__ __forceinline__ double dpp_quad_f64(double v) {
    unsigned long long u; __builtin_memcpy(&u, &v, 8);
    int lo = (int)(unsigned)(u & 0xFFFFFFFFull);
    int hi = (int)(unsigned)(u >> 32);
    lo = __builtin_amdgcn_update_dpp(0, lo, CTRL, 0xF, 0xF, true);
    hi = __builtin_amdgcn_update_dpp(0, hi, CTRL, 0xF, 0xF, true);
    unsigned long long r = (((unsigned long long)(unsigned)hi) << 32) | (unsigned)lo;
    double d; __builtin_memcpy(&d, &r, 8); return d;
}

// ---------- dtype detect + init ----------
__global__ void detect_and_init(const unsigned* __restrict__ spk,
                                int* __restrict__ flag, float* __restrict__ sums)
{
    unsigned w = spk[threadIdx.x];
    bool ok = (w == 0u) || (w == 0x3F800000u);
    unsigned long long vote = __ballot(ok);
    if (threadIdx.x == 0) {
        flag[0] = (vote == 0xFFFFFFFFFFFFFFFFull) ? 0 : 1;  // 0=f32, 1=bf16
        sums[0] = 0.f; sums[1] = 0.f; sums[2] = 0.f;
    }
}

// ---------- layer-0: pack spikes AND interleave to the 4-bit index stream ----------
// Thread per (n, g, site); output word (n,g,site,q): nibble j = bits of t=8q+j
// across the 4 cins of group g.
__global__ __launch_bounds__(256)
void pack_interleave(const void* __restrict__ ginv, unsigned* __restrict__ idx0,
                     const int* __restrict__ flag)
{
    const int gid = blockIdx.x * 256 + threadIdx.x;   // 4*32*256 = 32768
    if (gid >= 32768) return;
    const int site = gid & 255;
    const int g    = (gid >> 8) & 31;
    const int n    = gid >> 13;

    unsigned m[4];
    #pragma unroll
    for (int k = 0; k < 4; ++k) {
        const size_t ebase = ((size_t)(n * 128 + 4 * g + k) * 256 + site) * TT;
        unsigned mask = 0u;
        if (flag[0]) {
            const uint4* p = (const uint4*)((const unsigned short*)ginv + ebase);
            #pragma unroll
            for (int q = 0; q < 4; ++q) {
                uint4 a = p[q];
                unsigned wd[4] = {a.x, a.y, a.z, a.w};
                #pragma unroll
                for (int mm = 0; mm < 4; ++mm) {
                    const int t = q * 8 + mm * 2;
                    mask |= (wd[mm] & 0xFFFFu) ? (1u << t)       : 0u;
                    mask |= (wd[mm] >> 16)     ? (1u << (t + 1)) : 0u;
                }
            }
        } else {
            const float4* p = (const float4*)((const float*)ginv + ebase);
            #pragma unroll
            for (int j = 0; j < 8; ++j) {
                float4 v = p[j];
                mask |= (v.x != 0.f) ? (1u << (j * 4 + 0)) : 0u;
                mask |= (v.y != 0.f) ? (1u << (j * 4 + 1)) : 0u;
                mask |= (v.z != 0.f) ? (1u << (j * 4 + 2)) : 0u;
                mask |= (v.w != 0.f) ? (1u << (j * 4 + 3)) : 0u;
            }
        }
        m[k] = mask;
    }
    unsigned w[4];
    #pragma unroll
    for (int q = 0; q < 4; ++q)
        w[q] =  spread4((m[0] >> (8 * q)) & 0xFFu)
             | (spread4((m[1] >> (8 * q)) & 0xFFu) << 1)
             | (spread4((m[2] >> (8 * q)) & 0xFFu) << 2)
             | (spread4((m[3] >> (8 * q)) & 0xFFu) << 3);
    *(uint4*)(idx0 + (size_t)gid * 4) = make_uint4(w[0], w[1], w[2], w[3]);
}

// ---------- fused ConvT(stride2,k3,pad1, w*2) + CUBA scan ----------
// Grid: x = site chunk, y = co, z = parity class. Per class, S = nTap slabs
// partition the cin-groups (tid = site_local*S + slab) so every thread does
// the same number of tap-group iterations; slab partials combine via DPP
// quad-perm butterflies (register-only). Input is the precomputed 4-bit
// index stream; output stream is emitted with atomicOr (buffer pre-zeroed).
template<int CIN, int COUT, bool LAST>
__global__ __launch_bounds__(256)
void cuba_layer(const unsigned* __restrict__ idxIn, const void* __restrict__ wptr,
                void* __restrict__ goutv, unsigned* __restrict__ idxOut,
                int N, int Hi, int Wi, float* __restrict__ sumOut,
                const int* __restrict__ flag)
{
    constexpr int G = CIN / 4;
    const bool isbf = (flag[0] != 0);
    const int Ho = 2 * Hi - 1, Wo = 2 * Wi - 1;
    const int co = (int)blockIdx.y;
    const int zz = 3 - (int)blockIdx.z;          // heavy class first
    const int po = zz >> 1, pw = zz & 1;
    const int lg = po + pw;                      // log2(slabs)
    const int S  = 1 << lg;                      // slabs == nTap
    const int nH = Hi - po, nW = Wi - pw;
    const int sites = N * nH * nW;               // sites in this class (per co)
    const int spb = 256 >> lg;                   // sites per block
    const int siteBase = (int)blockIdx.x * spb;
    if (siteBase >= sites) return;               // dead block (uniform)

    // LUT[group][tap][idx]: sequential f64 sum of selected 2*w over the 4 cins.
    __shared__ double lut[G][4][16];
    {
        const unsigned short* w16 = (const unsigned short*)wptr;
        const float* w32 = (const float*)wptr;
        const int entries = G * S * 16;
        for (int e = threadIdx.x; e < entries; e += 256) {
            const int idx = e & 15;
            const int tp  = (e >> 4) & (S - 1);
            const int g   = e >> (4 + lg);
            const int v = (po && (tp >= (pw ? 2 : 1))) ? 1 : 0;
            const int h = pw ? (tp & 1) : 0;
            const int kh = v ? 0 : (po ? 2 : 1);
            const int kw = h ? 0 : (pw ? 2 : 1);
            const int wof = kh * 3 + kw;
            double s = 0.0;
            #pragma unroll
            for (int k = 0; k < 4; ++k) {
                if ((idx >> k) & 1) {
                    const int wi = ((4 * g + k) * COUT + co) * 9 + wof;
                    const float wraw = isbf ? bf16_bits_to_f32(w16[wi]) : w32[wi];
                    s += 2.0 * (double)wraw;     // weight_scale=2 folded (exact)
                }
            }
            lut[g][tp][idx] = s;
        }
    }
    __syncthreads();

    const int slab = (int)threadIdx.x & (S - 1);
    const int siteIdx = siteBase + ((int)threadIdx.x >> lg);
    const bool valid = siteIdx < sites;
    float cnt = 0.f;

    if (valid) {
        const int b  = siteIdx % nW;
        const int t1 = siteIdx / nW;
        const int a  = t1 % nH;
        const int n  = t1 / nH;
        const int oh = 2 * a + po, ow = 2 * b + pw;
        const int plane = Hi * Wi;

        const int siteA = a * Wi + b;
        const int siteB = siteA + 1;
        const int siteC = siteA + Wi;
        const int siteD = siteC + 1;

        double acc[TT];
        #pragma unroll
        for (int t = 0; t < TT; ++t) acc[t] = 0.0;

        const int Gs = G >> lg;                  // groups per slab
        for (int gi = 0; gi < Gs; ++gi) {
            const int g = slab * Gs + gi;
            const unsigned* ibase = idxIn + (size_t)(n * G + g) * plane * 4;

            auto doTap = [&](int site, int tp) {
                const uint4 w4 = *(const uint4*)(ibase + (size_t)site * 4);
                const unsigned wd[4] = {w4.x, w4.y, w4.z, w4.w};
                #pragma unroll
                for (int q = 0; q < 4; ++q) {
                    #pragma unroll
                    for (int j = 0; j < 8; ++j)
                        acc[q * 8 + j] += lut[g][tp][(wd[q] >> (4 * j)) & 0xFu];
                }
            };

            doTap(siteA, 0);
            if (pw) doTap(siteB, 1);             // block-uniform branches
            if (po) {
                doTap(siteC, pw ? 2 : 1);
                if (pw) doTap(siteD, 3);
            }
        }

        // Combine slab partials across the quad (register-only DPP).
        if (S >= 2) {
            #pragma unroll
            for (int t = 0; t < TT; ++t) acc[t] += dpp_quad_f64<0xB1>(acc[t]);
        }
        if (S == 4) {
            #pragma unroll
            for (int t = 0; t < TT; ++t) acc[t] += dpp_quad_f64<0x4E>(acc[t]);
        }

        // CUBA scan (identical on all slabs of a site).
        unsigned mask = 0u;
        if (isbf) {
            float cur = 0.f, vol = 0.f;
            #pragma unroll
            for (int t = 0; t < TT; ++t) {
                const float z = f64_to_bf16_f32(acc[t]);
                cur = round_bf16_f32(0.5f * cur + z);
                vol = round_bf16_f32(0.5f * vol + cur);
                const bool fire = (vol >= 1.0f);
                mask |= fire ? (1u << t) : 0u;
                vol = fire ? 0.f : vol;
            }
        } else {
            double cur = 0.0, vol = 0.0;
            #pragma unroll
            for (int t = 0; t < TT; ++t) {
                cur = fma(0.5, cur, acc[t]);
                vol = fma(0.5, vol, cur);
                const bool fire = (vol >= 1.0);
                mask |= fire ? (1u << t) : 0u;
                vol = fire ? 0.0 : vol;
            }
        }
        cnt = (slab == 0) ? (float)__popc(mask) : 0.f;

        if (LAST) {
            const int gidOut = ((n * COUT + co) * Ho + oh) * Wo + ow;
            if (isbf) {
                uint4* ob = (uint4*)((unsigned short*)goutv + (size_t)gidOut * TT);
                const int qn = 4 >> lg;          // quads per slab (striped store)
                for (int qi = 0; qi < qn; ++qi) {
                    const int q = slab * qn + qi;
                    unsigned wd[4];
                    #pragma unroll
                    for (int m2 = 0; m2 < 4; ++m2) {
                        const int t = (q * 4 + m2) * 2;
                        wd[m2] = (((mask >> t) & 1u) ? 0x3F80u : 0u)
                               | (((mask >> (t + 1)) & 1u) ? 0x3F800000u : 0u);
                    }
                    ob[q] = make_uint4(wd[0], wd[1], wd[2], wd[3]);
                }
            } else {
                float4* ob = (float4*)((float*)goutv + (size_t)gidOut * TT);
                const int jn = 8 >> lg;          // quads per slab (striped store)
                for (int ji = 0; ji < jn; ++ji) {
                    const int j = slab * jn + ji;
                    float4 s4;
                    s4.x = (mask >> (j * 4 + 0)) & 1u ? 1.0f : 0.0f;
                    s4.y = (mask >> (j * 4 + 1)) & 1u ? 1.0f : 0.0f;
                    s4.z = (mask >> (j * 4 + 2)) & 1u ? 1.0f : 0.0f;
                    s4.w = (mask >> (j * 4 + 3)) & 1u ? 1.0f : 0.0f;
                    ob[j] = s4;
                }
            }
        } else {
            // Emit interleaved index stream for the next layer (pre-zeroed).
            const int osite = oh * Wo + ow;
            unsigned* obase = idxOut
                + ((size_t)(n * (COUT / 4) + (co >> 2)) * (Ho * Wo) + osite) * 4;
            const int qn = 4 >> lg;              // q-words per slab (striped)
            for (int qi = 0; qi < qn; ++qi) {
                const int q = slab * qn + qi;
                const unsigned bits = spread4((mask >> (8 * q)) & 0xFFu) << (co & 3);
                if (bits) atomicOr(obase + q, bits);
            }
        }
    }

    // Wave-level (64) count reduction; per-layer sums are integers < 2^24 so
    // fp32 atomic accumulation is exact.
    #pragma unroll
    for (int o = 32; o >= 1; o >>= 1) cnt += __shfl_down(cnt, o);
    if ((threadIdx.x & 63) == 0 && cnt > 0.f) atomicAdd(sumOut, cnt);
}

__global__ void finalize_counts(const float* __restrict__ sums,
                                void* __restrict__ out, const int* __restrict__ flag)
{
    int i = threadIdx.x;
    if (i < 3) {
        const float numel[3] = {7872512.f, 15239168.f, 3748096.f};
        float v = sums[i] / numel[i];
        if (flag[0]) ((unsigned short*)out)[3748096 + i] = f32_to_bf16_rne(v);
        else         ((float*)out)[3748096 + i] = v;
    }
}

extern "C" void kernel_launch(void* const* d_in, const int* in_sizes, int n_in,
                              void* d_out, int out_size, void* d_ws, size_t ws_size,
                              hipStream_t stream)
{
    const void* x  = d_in[0];  // [4,128,16,16,32] spikes (f32 or bf16)
    const void* w1 = d_in[1];  // [128,64,3,3]
    const void* w2 = d_in[2];  // [64,32,3,3]
    const void* w3 = d_in[3];  // [32,2,3,3]

    // Interleaved 4-bit index streams (one u32 per (n,group,site,q)). ~3.42 MB.
    unsigned* idx0 = (unsigned*)d_ws;          // 4*32*256*4  = 131,072 words
    unsigned* idx1 = idx0 + 131072;            // 4*16*961*4  = 246,016 words
    unsigned* idx2 = idx1 + 246016;            // 4*8*3721*4  = 476,288 words
    float* sums = (float*)(idx2 + 476288);     // 3 floats
    int*   flag = (int*)(sums + 3);

    detect_and_init<<<1, 64, 0, stream>>>((const unsigned*)x, flag, sums);
    hipMemsetAsync(idx1, 0, (246016 + 476288) * sizeof(unsigned), stream);
    pack_interleave<<<128, 256, 0, stream>>>(x, idx0, flag);

    // Grid: x = site chunk, y = co, z = parity class (S=nTap slabs per class).
    // L1: 128->64, 16x16 -> 31x31. max blocks over classes = 15
    cuba_layer<128, 64, false><<<dim3(15, 64, 4), 256, 0, stream>>>(
        idx0, w1, nullptr, idx1, 4, 16, 16, sums + 0, flag);
    // L2: 64->32, 31x31 -> 61x61. max blocks = 57
    cuba_layer<64, 32, false><<<dim3(57, 32, 4), 256, 0, stream>>>(
        idx1, w2, nullptr, idx2, 4, 31, 31, sums + 1, flag);
    // L3: 32->2, 61x61 -> 121x121. max blocks = 225
    cuba_layer<32, 2, true><<<dim3(225, 2, 4), 256, 0, stream>>>(
        idx2, w3, d_out, nullptr, 4, 61, 61, sums + 2, flag);

    finalize_counts<<<1, 64, 0, stream>>>(sums, d_out, flag);
}

// Round 4
// 392.992 us; speedup vs baseline: 1.3434x; 1.3434x over previous
//
#include <hip/hip_runtime.h>

#define TT 32

// ---------- bf16 helpers (OCP bfloat16, RNE) ----------
__device__ __forceinline__ float bf16_bits_to_f32(unsigned short u) {
    unsigned v = ((unsigned)u) << 16; float f; __builtin_memcpy(&f, &v, 4); return f;
}
__device__ __forceinline__ unsigned short f32_to_bf16_rne(float f) {
    unsigned u; __builtin_memcpy(&u, &f, 4);
    u += 0x7FFFu + ((u >> 16) & 1u);            // round-to-nearest-even
    return (unsigned short)(u >> 16);
}
__device__ __forceinline__ float round_bf16_f32(float f) {  // f32 -> bf16 -> f32 value
    return bf16_bits_to_f32(f32_to_bf16_rne(f));
}
// Correctly-rounded f64 -> bf16 (single rounding): round-to-odd to f32, then RNE.
__device__ __forceinline__ float f64_to_bf16_f32(double d) {
    float fz = __double2float_rz(d);
    if ((double)fz != d) {
        unsigned u; __builtin_memcpy(&u, &fz, 4); u |= 1u; __builtin_memcpy(&fz, &u, 4);
    }
    return round_bf16_f32(fz);
}
// Spread the 8 bits of b to positions 0,4,8,...,28 (Morton-4).
__device__ __forceinline__ unsigned spread4(unsigned b) {
    unsigned x = (b | (b << 12)) & 0x000F000Fu;
    x = (x | (x << 6)) & 0x03030303u;
    x = (x | (x << 3)) & 0x11111111u;
    return x;
}

// ---------- dtype detect + init ----------
__global__ void detect_and_init(const unsigned* __restrict__ spk,
                                int* __restrict__ flag, float* __restrict__ sums)
{
    unsigned w = spk[threadIdx.x];
    bool ok = (w == 0u) || (w == 0x3F800000u);
    unsigned long long vote = __ballot(ok);
    if (threadIdx.x == 0) {
        flag[0] = (vote == 0xFFFFFFFFFFFFFFFFull) ? 0 : 1;  // 0=f32, 1=bf16
        sums[0] = 0.f; sums[1] = 0.f; sums[2] = 0.f;
    }
}

// ---------- layer-0: pack spikes into SoA 4-bit index planes ----------
// Word (q, n,g,site): nibble j = spike bits of t=8q+j across the 4 cins of g.
__global__ __launch_bounds__(256)
void pack_interleave(const void* __restrict__ ginv, unsigned* __restrict__ idx0,
                     const int* __restrict__ flag)
{
    const int gid = blockIdx.x * 256 + threadIdx.x;   // 4*32*256 = 32768
    if (gid >= 32768) return;
    const int site = gid & 255;
    const int g    = (gid >> 8) & 31;
    const int n    = gid >> 13;

    unsigned m[4];
    #pragma unroll
    for (int k = 0; k < 4; ++k) {
        const size_t ebase = ((size_t)(n * 128 + 4 * g + k) * 256 + site) * TT;
        unsigned mask = 0u;
        if (flag[0]) {
            const uint4* p = (const uint4*)((const unsigned short*)ginv + ebase);
            #pragma unroll
            for (int q = 0; q < 4; ++q) {
                uint4 a = p[q];
                unsigned wd[4] = {a.x, a.y, a.z, a.w};
                #pragma unroll
                for (int mm = 0; mm < 4; ++mm) {
                    const int t = q * 8 + mm * 2;
                    mask |= (wd[mm] & 0xFFFFu) ? (1u << t)       : 0u;
                    mask |= (wd[mm] >> 16)     ? (1u << (t + 1)) : 0u;
                }
            }
        } else {
            const float4* p = (const float4*)((const float*)ginv + ebase);
            #pragma unroll
            for (int j = 0; j < 8; ++j) {
                float4 v = p[j];
                mask |= (v.x != 0.f) ? (1u << (j * 4 + 0)) : 0u;
                mask |= (v.y != 0.f) ? (1u << (j * 4 + 1)) : 0u;
                mask |= (v.z != 0.f) ? (1u << (j * 4 + 2)) : 0u;
                mask |= (v.w != 0.f) ? (1u << (j * 4 + 3)) : 0u;
            }
        }
        m[k] = mask;
    }
    #pragma unroll
    for (int q = 0; q < 4; ++q) {
        const unsigned w =  spread4((m[0] >> (8 * q)) & 0xFFu)
                         | (spread4((m[1] >> (8 * q)) & 0xFFu) << 1)
                         | (spread4((m[2] >> (8 * q)) & 0xFFu) << 2)
                         | (spread4((m[3] >> (8 * q)) & 0xFFu) << 3);
        idx0[q * 32768 + gid] = w;
    }
}

// ---------- mid-layer: masks -> SoA 4-bit index planes (plain stores) ----------
template<int C, int PLANE>   // C = channels at this interface
__global__ __launch_bounds__(256)
void pack_mid(const unsigned* __restrict__ masks, unsigned* __restrict__ idx)
{
    constexpr int G = C / 4;
    constexpr int TOT = 4 * G * PLANE;
    const int gid = blockIdx.x * 256 + threadIdx.x;
    if (gid >= TOT) return;
    const int site = gid % PLANE;
    const int g    = (gid / PLANE) % G;
    const int n    = gid / (PLANE * G);
    unsigned m[4];
    #pragma unroll
    for (int k = 0; k < 4; ++k)
        m[k] = masks[(n * C + 4 * g + k) * PLANE + site];
    #pragma unroll
    for (int q = 0; q < 4; ++q) {
        const unsigned w =  spread4((m[0] >> (8 * q)) & 0xFFu)
                         | (spread4((m[1] >> (8 * q)) & 0xFFu) << 1)
                         | (spread4((m[2] >> (8 * q)) & 0xFFu) << 2)
                         | (spread4((m[3] >> (8 * q)) & 0xFFu) << 3);
        idx[q * TOT + gid] = w;
    }
}

// ---------- fused ConvT(stride2,k3,pad1, w*2) + CUBA scan ----------
// Grid: x = site chunk, y = co, z = parity class (heavy first). Thread = site:
// g is loop-uniform and tap block-uniform, so a wave reads at most 16 distinct
// LUT entries -> conflict-free broadcast ds_read_b64. t processed in 4 passes
// of 8 (acc[8], scan state carried) to keep VGPR pressure low.
template<int CIN, int COUT, bool LAST>
__global__ __launch_bounds__(256, 4)
void cuba_layer(const unsigned* __restrict__ idxIn, const void* __restrict__ wptr,
                void* __restrict__ goutv, unsigned* __restrict__ maskOut,
                int N, int Hi, int Wi, float* __restrict__ sumOut,
                const int* __restrict__ flag)
{
    constexpr int G = CIN / 4;
    const bool isbf = (flag[0] != 0);
    const int Ho = 2 * Hi - 1, Wo = 2 * Wi - 1;
    const int co = (int)blockIdx.y;
    const int zz = 3 - (int)blockIdx.z;          // heavy class first
    const int po = zz >> 1, pw = zz & 1;
    const int lg = po + pw;
    const int nTap = 1 << lg;
    const int nH = Hi - po, nW = Wi - pw;
    const int sites = N * nH * nW;               // sites in this class (per co)
    const int siteBase = (int)blockIdx.x * 256;
    if (siteBase >= sites) return;               // dead block (uniform)

    // LUT[group][tap][idx]: sequential f64 sum of selected 2*w over the 4 cins.
    __shared__ double lut[G][4][16];
    {
        const unsigned short* w16 = (const unsigned short*)wptr;
        const float* w32 = (const float*)wptr;
        const int entries = G * nTap * 16;
        for (int e = threadIdx.x; e < entries; e += 256) {
            const int idx = e & 15;
            const int tp  = (e >> 4) & (nTap - 1);
            const int g   = e >> (4 + lg);
            const int v = (po && (tp >= (pw ? 2 : 1))) ? 1 : 0;
            const int h = pw ? (tp & 1) : 0;
            const int kh = v ? 0 : (po ? 2 : 1);
            const int kw = h ? 0 : (pw ? 2 : 1);
            const int wof = kh * 3 + kw;
            double s = 0.0;
            #pragma unroll
            for (int k = 0; k < 4; ++k) {
                if ((idx >> k) & 1) {
                    const int wi = ((4 * g + k) * COUT + co) * 9 + wof;
                    const float wraw = isbf ? bf16_bits_to_f32(w16[wi]) : w32[wi];
                    s += 2.0 * (double)wraw;     // weight_scale=2 folded (exact)
                }
            }
            lut[g][tp][idx] = s;
        }
    }
    __syncthreads();

    const int siteIdx = siteBase + (int)threadIdx.x;
    float cnt = 0.f;

    if (siteIdx < sites) {
        const int b  = siteIdx % nW;
        const int t1 = siteIdx / nW;
        const int a  = t1 % nH;
        const int n  = t1 / nH;
        const int oh = 2 * a + po, ow = 2 * b + pw;
        const int plane = Hi * Wi;
        const int QT = N * G * plane;            // words per q-plane

        const int siteA = a * Wi + b;
        const int siteB = siteA + 1;
        const int siteC = siteA + Wi;
        const int siteD = siteC + 1;

        unsigned mask = 0u;
        float  curF = 0.f, volF = 0.f;
        double curD = 0.0, volD = 0.0;

        #pragma unroll 1
        for (int p = 0; p < 4; ++p) {
            double acc[8];
            #pragma unroll
            for (int j = 0; j < 8; ++j) acc[j] = 0.0;

            const unsigned* pb = idxIn + (size_t)p * QT + (size_t)(n * G) * plane;
            for (int g = 0; g < G; ++g) {
                const unsigned* bp = pb + (size_t)g * plane;
                {
                    const unsigned w = bp[siteA];
                    #pragma unroll
                    for (int j = 0; j < 8; ++j)
                        acc[j] += lut[g][0][(w >> (4 * j)) & 0xFu];
                }
                if (pw) {
                    const unsigned w = bp[siteB];
                    #pragma unroll
                    for (int j = 0; j < 8; ++j)
                        acc[j] += lut[g][1][(w >> (4 * j)) & 0xFu];
                }
                if (po) {
                    const unsigned w = bp[siteC];
                    #pragma unroll
                    for (int j = 0; j < 8; ++j)
                        acc[j] += lut[g][pw ? 2 : 1][(w >> (4 * j)) & 0xFu];
                }
                if (po && pw) {
                    const unsigned w = bp[siteD];
                    #pragma unroll
                    for (int j = 0; j < 8; ++j)
                        acc[j] += lut[g][3][(w >> (4 * j)) & 0xFu];
                }
            }

            // CUBA scan, 8 steps with carried state.
            if (isbf) {
                #pragma unroll
                for (int j = 0; j < 8; ++j) {
                    const int t = p * 8 + j;
                    const float z = f64_to_bf16_f32(acc[j]);
                    curF = round_bf16_f32(0.5f * curF + z);
                    volF = round_bf16_f32(0.5f * volF + curF);
                    const bool fire = (volF >= 1.0f);
                    mask |= fire ? (1u << t) : 0u;
                    volF = fire ? 0.f : volF;
                }
            } else {
                #pragma unroll
                for (int j = 0; j < 8; ++j) {
                    const int t = p * 8 + j;
                    curD = fma(0.5, curD, acc[j]);
                    volD = fma(0.5, volD, curD);
                    const bool fire = (volD >= 1.0);
                    mask |= fire ? (1u << t) : 0u;
                    volD = fire ? 0.0 : volD;
                }
            }
        }
        cnt = (float)__popc(mask);

        const int gidOut = ((n * COUT + co) * Ho + oh) * Wo + ow;
        if (LAST) {
            if (isbf) {
                uint4* ob = (uint4*)((unsigned short*)goutv + (size_t)gidOut * TT);
                #pragma unroll
                for (int q = 0; q < 4; ++q) {
                    unsigned wd[4];
                    #pragma unroll
                    for (int m2 = 0; m2 < 4; ++m2) {
                        const int t = (q * 4 + m2) * 2;
                        wd[m2] = (((mask >> t) & 1u) ? 0x3F80u : 0u)
                               | (((mask >> (t + 1)) & 1u) ? 0x3F800000u : 0u);
                    }
                    ob[q] = make_uint4(wd[0], wd[1], wd[2], wd[3]);
                }
            } else {
                float4* ob = (float4*)((float*)goutv + (size_t)gidOut * TT);
                #pragma unroll
                for (int j = 0; j < 8; ++j) {
                    float4 s4;
                    s4.x = (mask >> (j * 4 + 0)) & 1u ? 1.0f : 0.0f;
                    s4.y = (mask >> (j * 4 + 1)) & 1u ? 1.0f : 0.0f;
                    s4.z = (mask >> (j * 4 + 2)) & 1u ? 1.0f : 0.0f;
                    s4.w = (mask >> (j * 4 + 3)) & 1u ? 1.0f : 0.0f;
                    ob[j] = s4;
                }
            }
        } else {
            maskOut[gidOut] = mask;
        }
    }

    // Wave-level (64) count reduction; per-layer sums are integers < 2^24 so
    // fp32 atomic accumulation is exact.
    #pragma unroll
    for (int o = 32; o >= 1; o >>= 1) cnt += __shfl_down(cnt, o);
    if ((threadIdx.x & 63) == 0 && cnt > 0.f) atomicAdd(sumOut, cnt);
}

__global__ void finalize_counts(const float* __restrict__ sums,
                                void* __restrict__ out, const int* __restrict__ flag)
{
    int i = threadIdx.x;
    if (i < 3) {
        const float numel[3] = {7872512.f, 15239168.f, 3748096.f};
        float v = sums[i] / numel[i];
        if (flag[0]) ((unsigned short*)out)[3748096 + i] = f32_to_bf16_rne(v);
        else         ((float*)out)[3748096 + i] = v;
    }
}

extern "C" void kernel_launch(void* const* d_in, const int* in_sizes, int n_in,
                              void* d_out, int out_size, void* d_ws, size_t ws_size,
                              hipStream_t stream)
{
    const void* x  = d_in[0];  // [4,128,16,16,32] spikes (f32 or bf16)
    const void* w1 = d_in[1];  // [128,64,3,3]
    const void* w2 = d_in[2];  // [64,32,3,3]
    const void* w3 = d_in[3];  // [32,2,3,3]

    // A/B ping-pong (masks in A, index planes in B). Total ws ~ 3.81 MB.
    // Timeline: idx0->B; L1: B->A(masks); pack1: A->B(idx); L2: B->A(masks);
    // pack2: A->B(idx); L3: B->out.
    unsigned* bufA = (unsigned*)d_ws;          // 476,288 words
    unsigned* bufB = bufA + 476288;            // 476,288 words
    unsigned* idx0 = bufB;                     // 131,072 words used
    float* sums = (float*)(bufB + 476288);     // 3 floats
    int*   flag = (int*)(sums + 3);

    detect_and_init<<<1, 64, 0, stream>>>((const unsigned*)x, flag, sums);
    pack_interleave<<<128, 256, 0, stream>>>(x, idx0, flag);

    // Grid: x = site chunk, y = co, z = parity class.
    // L1: 128->64, 16x16 -> 31x31. max class sites 1024 -> x=4
    cuba_layer<128, 64, false><<<dim3(4, 64, 4), 256, 0, stream>>>(
        idx0, w1, nullptr, bufA, 4, 16, 16, sums + 0, flag);
    pack_mid<64, 961><<<241, 256, 0, stream>>>(bufA, bufB);
    // L2: 64->32, 31x31 -> 61x61. max class sites 3844 -> x=16
    cuba_layer<64, 32, false><<<dim3(16, 32, 4), 256, 0, stream>>>(
        bufB, w2, nullptr, bufA, 4, 31, 31, sums + 1, flag);
    pack_mid<32, 3721><<<466, 256, 0, stream>>>(bufA, bufB);
    // L3: 32->2, 61x61 -> 121x121. max class sites 14884 -> x=59
    cuba_layer<32, 2, true><<<dim3(59, 2, 4), 256, 0, stream>>>(
        bufB, w3, d_out, nullptr, 4, 61, 61, sums + 2, flag);

    finalize_counts<<<1, 64, 0, stream>>>(sums, d_out, flag);
}